// Round 1
// baseline (341.866 us; speedup 1.0000x reference)
//
#include <hip/hip_runtime.h>
#include <stdint.h>

// Problem constants
#define A_    32
#define C_    8
#define B_    32
#define D_    16
#define KK_   9
#define KKA_  288          // KK * A
#define BD_   512          // B * D
#define NB_   4            // batch
#define HW_   14
#define L_    196          // 14*14
#define NSITES 784         // NB_ * L_
#define SITE_UINTS (KKA_ * (BD_/2))   // 73728 uints (bf16 pairs)
#define SITE_BYTES (SITE_UINTS * 4)   // 294912 B

// round-to-nearest-even fp32 -> bf16 (finite inputs)
__device__ __forceinline__ uint32_t f2bf(float f) {
    uint32_t u = __float_as_uint(f);
    return (u + 0x7fffu + ((u >> 16) & 1u)) >> 16;
}

// ---------------- Kernel 1: pose_out = einsum('kpc,skc->skp') ----------------
// grid: (ceil(chunk/16), 288); block: 256
// thread t computes bd pair (2t, 2t+1) for 16 sites; W tile held in 16 regs.
__global__ __launch_bounds__(256) void k_pose_out(
    const float* __restrict__ pose, const float* __restrict__ W,
    uint32_t* __restrict__ po, int s0, int s_end)
{
    const int t  = threadIdx.x;
    const int kk = blockIdx.y;
    const int site0 = s0 + blockIdx.x * 16;

    const int p = kk >> 5;       // patch position (0..8)
    const int a = kk & 31;       // input capsule
    const int ky = p / 3 - 1;
    const int kx = p % 3 - 1;

    __shared__ float x_lds[16][8];

    if (t < 128) {
        const int ss = t >> 3, c = t & 7;
        const int st = site0 + ss;
        float val = 0.f;
        if (st < NSITES) {
            const int b  = st / L_;
            const int l  = st - b * L_;
            const int oh = l / HW_;
            const int ow = l - oh * HW_;
            const int y = oh + ky, x = ow + kx;
            if (y >= 0 && y < HW_ && x >= 0 && x < HW_) {
                val = pose[(((size_t)b * (A_ * C_) + a * C_ + c) * HW_ + y) * HW_ + x];
            }
        }
        x_lds[ss][c] = val;
    }

    // W[kk][2t..2t+1][0..7] : 16 consecutive floats
    const float4* Wp = reinterpret_cast<const float4*>(W + (size_t)kk * (BD_ * C_) + (size_t)t * 16);
    const float4 w0 = Wp[0], w1 = Wp[1], w2 = Wp[2], w3 = Wp[3];

    __syncthreads();

    uint32_t* out_base = po + (size_t)(site0 - s0) * SITE_UINTS + (size_t)kk * (BD_/2) + t;

    #pragma unroll
    for (int ss = 0; ss < 16; ++ss) {
        const float4 xa = *reinterpret_cast<const float4*>(&x_lds[ss][0]);
        const float4 xb = *reinterpret_cast<const float4*>(&x_lds[ss][4]);
        float o0 = w0.x*xa.x + w0.y*xa.y + w0.z*xa.z + w0.w*xa.w
                 + w1.x*xb.x + w1.y*xb.y + w1.z*xb.z + w1.w*xb.w;
        float o1 = w2.x*xa.x + w2.y*xa.y + w2.z*xa.z + w2.w*xa.w
                 + w3.x*xb.x + w3.y*xb.y + w3.z*xb.z + w3.w*xb.w;
        if (site0 + ss < s_end) {
            out_base[(size_t)ss * SITE_UINTS] = f2bf(o0) | (f2bf(o1) << 16);
        }
    }
}

// ---------------- Kernel 2: dynamic routing, one block per site ----------------
// block = 256 (4 waves). lane ln owns bd = ln*8 .. ln*8+7  (B = ln>>1, D-half = ln&1).
// wave w owns rows kk = 4r + w  -> per-row softmax is in-wave shfl only.
__device__ __forceinline__ void decode8(const uint4 pk, float* f) {
    f[0] = __uint_as_float(pk.x << 16); f[1] = __uint_as_float(pk.x & 0xffff0000u);
    f[2] = __uint_as_float(pk.y << 16); f[3] = __uint_as_float(pk.y & 0xffff0000u);
    f[4] = __uint_as_float(pk.z << 16); f[5] = __uint_as_float(pk.z & 0xffff0000u);
    f[6] = __uint_as_float(pk.w << 16); f[7] = __uint_as_float(pk.w & 0xffff0000u);
}

__device__ __forceinline__ void reduce_squash(const float* s_acc, float scale,
                                              int w, int ln, float* s_red, float* v)
{
    #pragma unroll
    for (int j = 0; j < 8; ++j) s_red[w * BD_ + ln * 8 + j] = s_acc[j];
    __syncthreads();
    float msq = 0.f, st8[8];
    #pragma unroll
    for (int j = 0; j < 8; ++j) {
        float tv = s_red[ln*8 + j] + s_red[BD_ + ln*8 + j]
                 + s_red[2*BD_ + ln*8 + j] + s_red[3*BD_ + ln*8 + j];
        tv *= scale;
        st8[j] = tv;
        msq += tv * tv;
    }
    __syncthreads();   // s_red reused next pass
    msq += __shfl_xor(msq, 1, 64);   // partner holds other half of D
    const float fac = sqrtf(msq) / (1.f + msq);   // squash: s * |s|/(1+|s|^2)
    #pragma unroll
    for (int j = 0; j < 8; ++j) v[j] = st8[j] * fac;
}

__global__ __launch_bounds__(256) void k_route(
    const uint32_t* __restrict__ po, float* __restrict__ out, int s0)
{
    const int t  = threadIdx.x;
    const int w  = t >> 6;
    const int ln = t & 63;
    const int site = s0 + blockIdx.x;

    __shared__ float logits[KKA_ * B_];   // 36 KB, rows wave-private
    __shared__ float s_red[4 * BD_];      // 8 KB

    const uint32_t* sbase = po + (size_t)blockIdx.x * SITE_UINTS + (size_t)ln * 4;

    float v[8], s_acc[8];

    // ---- pass 1: c uniform = 1/32 -> s1 -> v1
    #pragma unroll
    for (int j = 0; j < 8; ++j) s_acc[j] = 0.f;
    for (int r = 0; r < KKA_ / 4; ++r) {
        const int kk = r * 4 + w;
        const uint4 pk = *reinterpret_cast<const uint4*>(sbase + (size_t)kk * (BD_/2));
        float f[8]; decode8(pk, f);
        #pragma unroll
        for (int j = 0; j < 8; ++j) s_acc[j] += f[j];
    }
    reduce_squash(s_acc, 1.f / 32.f, w, ln, s_red, v);

    // ---- fused passes: logit update (v_i) + softmax -> c_{i+1} -> s_{i+1} -> v_{i+1}
    for (int iter = 0; iter < 2; ++iter) {
        #pragma unroll
        for (int j = 0; j < 8; ++j) s_acc[j] = 0.f;
        for (int r = 0; r < KKA_ / 4; ++r) {
            const int kk = r * 4 + w;
            const uint4 pk = *reinterpret_cast<const uint4*>(sbase + (size_t)kk * (BD_/2));
            float f[8]; decode8(pk, f);
            // u[kk,B] = sum_D v*po  (pair shfl completes the 16-wide D dot)
            float up = 0.f;
            #pragma unroll
            for (int j = 0; j < 8; ++j) up += v[j] * f[j];
            up += __shfl_xor(up, 1, 64);
            float lg;
            if (iter == 0) lg = up;
            else           lg = logits[kk * B_ + (ln >> 1)] + up;
            if ((ln & 1) == 0) logits[kk * B_ + (ln >> 1)] = lg;
            // softmax over B: masks 2..32 keep bit0 fixed -> exactly one lane per B
            float mx = lg;
            #pragma unroll
            for (int m = 2; m < 64; m <<= 1) mx = fmaxf(mx, __shfl_xor(mx, m, 64));
            const float e = __expf(lg - mx);
            float se = e;
            #pragma unroll
            for (int m = 2; m < 64; m <<= 1) se += __shfl_xor(se, m, 64);
            const float c = e * __builtin_amdgcn_rcpf(se);
            #pragma unroll
            for (int j = 0; j < 8; ++j) s_acc[j] += c * f[j];
        }
        reduce_squash(s_acc, 1.f, w, ln, s_red, v);
    }

    // ---- write v3: out[b][bd][l], bd = ln*8+j  (waves hold identical v; w0 stores)
    if (w == 0) {
        const int b = site / L_;
        const int l = site - b * L_;
        float* op = out + (size_t)b * BD_ * L_ + l;
        #pragma unroll
        for (int j = 0; j < 8; ++j) op[(size_t)(ln * 8 + j) * L_] = v[j];
    }
}

extern "C" void kernel_launch(void* const* d_in, const int* in_sizes, int n_in,
                              void* d_out, int out_size, void* d_ws, size_t ws_size,
                              hipStream_t stream) {
    const float* pose = (const float*)d_in[0];
    const float* W    = (const float*)d_in[1];
    float* out        = (float*)d_out;

    size_t max_chunk_sz = ws_size / (size_t)SITE_BYTES;
    int max_chunk = (max_chunk_sz > (size_t)NSITES) ? NSITES : (int)max_chunk_sz;
    if (max_chunk <= 0) return;   // workspace too small (shouldn't happen)

    for (int s0 = 0; s0 < NSITES; s0 += max_chunk) {
        const int chunk = (NSITES - s0 < max_chunk) ? (NSITES - s0) : max_chunk;
        const int s_end = s0 + chunk;
        dim3 g1((chunk + 15) / 16, KKA_, 1);
        k_pose_out<<<g1, dim3(256), 0, stream>>>(pose, W, (uint32_t*)d_ws, s0, s_end);
        k_route<<<dim3(chunk), dim3(256), 0, stream>>>((const uint32_t*)d_ws, out, s0);
    }
}

// Round 2
// 245.961 us; speedup vs baseline: 1.3899x; 1.3899x over previous
//
#include <hip/hip_runtime.h>
#include <stdint.h>

// Problem constants
#define A_    32
#define C_    8
#define B_    32
#define D_    16
#define KK_   9
#define KKA_  288          // KK * A
#define BD_   512          // B * D
#define NB_   4            // batch
#define HW_   14
#define L_    196          // 14*14
#define NSITES 784         // NB_ * L_
#define SITE_UINTS (KKA_ * (BD_/2))   // 73728 uints (bf16 pairs)
#define SITE_BYTES (SITE_UINTS * 4)   // 294912 B
#define NW    8            // waves per k_route block
#define NR    (KKA_ / NW)  // 36 rows per wave

// round-to-nearest-even fp32 -> bf16 (finite inputs)
__device__ __forceinline__ uint32_t f2bf(float f) {
    uint32_t u = __float_as_uint(f);
    return (u + 0x7fffu + ((u >> 16) & 1u)) >> 16;
}

// ---------------- Kernel 1: pose_out = einsum('kpc,skc->skp') ----------------
// grid: (ceil(chunk/16), 72); block: 256 = 4 waves, wave w owns kk = by*4+w.
// Lane ln holds W[kk][ln*8 .. ln*8+8][0..8] in 64 regs; produces 8 bd values
// per site -> one dwordx4 (16B) store per site-row.
__global__ __launch_bounds__(256) void k_pose_out(
    const float* __restrict__ pose, const float* __restrict__ W,
    uint32_t* __restrict__ po, int s0, int s_end)
{
    const int t  = threadIdx.x;
    const int w  = t >> 6;
    const int ln = t & 63;
    const int kk = blockIdx.y * 4 + w;
    const int site0 = s0 + blockIdx.x * 16;

    __shared__ float x_lds[4][16][8];   // [kk-local][site][c]

    // stage x: 4 kk-rows x 16 sites x 8 c = 512 values, 2 per thread
    #pragma unroll
    for (int it = 0; it < 2; ++it) {
        const int li  = t + 256 * it;
        const int kkl = li >> 7;
        const int rem = li & 127;
        const int ss  = rem >> 3;
        const int c   = rem & 7;
        const int kkg = blockIdx.y * 4 + kkl;
        const int p = kkg >> 5, a = kkg & 31;
        const int ky = p / 3 - 1, kx = p % 3 - 1;
        const int st = site0 + ss;
        float val = 0.f;
        if (st < NSITES) {
            const int b  = st / L_;
            const int l  = st - b * L_;
            const int oh = l / HW_;
            const int ow = l - oh * HW_;
            const int y = oh + ky, x = ow + kx;
            if (y >= 0 && y < HW_ && x >= 0 && x < HW_) {
                val = pose[(((size_t)b * (A_ * C_) + a * C_ + c) * HW_ + y) * HW_ + x];
            }
        }
        x_lds[kkl][ss][c] = val;
    }

    // W[kk][ln*8..+8][0..8] : 64 consecutive floats
    const float4* Wp = reinterpret_cast<const float4*>(
        W + (size_t)kk * (BD_ * C_) + (size_t)ln * 64);
    float4 wr[16];
    #pragma unroll
    for (int i = 0; i < 16; ++i) wr[i] = Wp[i];

    __syncthreads();

    uint32_t* ob = po + (size_t)(site0 - s0) * SITE_UINTS + (size_t)kk * (BD_/2) + ln * 4;

    #pragma unroll
    for (int ss = 0; ss < 16; ++ss) {
        const float4 xa = *reinterpret_cast<const float4*>(&x_lds[w][ss][0]);
        const float4 xb = *reinterpret_cast<const float4*>(&x_lds[w][ss][4]);
        float o[8];
        #pragma unroll
        for (int jj = 0; jj < 8; ++jj) {
            const float4 wa = wr[2*jj], wb = wr[2*jj+1];
            o[jj] = wa.x*xa.x + wa.y*xa.y + wa.z*xa.z + wa.w*xa.w
                  + wb.x*xb.x + wb.y*xb.y + wb.z*xb.z + wb.w*xb.w;
        }
        if (site0 + ss < s_end) {
            uint4 pk;
            pk.x = f2bf(o[0]) | (f2bf(o[1]) << 16);
            pk.y = f2bf(o[2]) | (f2bf(o[3]) << 16);
            pk.z = f2bf(o[4]) | (f2bf(o[5]) << 16);
            pk.w = f2bf(o[6]) | (f2bf(o[7]) << 16);
            *reinterpret_cast<uint4*>(ob + (size_t)ss * SITE_UINTS) = pk;
        }
    }
}

// ---------------- Kernel 2: dynamic routing, one block per site ----------------
// block = 512 (8 waves). lane ln owns bd = ln*8..+8 (B = ln>>1, D-half = ln&1).
// wave w owns rows kk = 8r + w -> per-row B-softmax is in-wave shfl only.
// No logits storage: logits_3 = <v1+v2, po> recomputed from registers.
__device__ __forceinline__ void decode8(const uint4 pk, float* f) {
    f[0] = __uint_as_float(pk.x << 16); f[1] = __uint_as_float(pk.x & 0xffff0000u);
    f[2] = __uint_as_float(pk.y << 16); f[3] = __uint_as_float(pk.y & 0xffff0000u);
    f[4] = __uint_as_float(pk.z << 16); f[5] = __uint_as_float(pk.z & 0xffff0000u);
    f[6] = __uint_as_float(pk.w << 16); f[7] = __uint_as_float(pk.w & 0xffff0000u);
}

__device__ __forceinline__ void reduce_squash(const float* s_acc, float scale,
                                              int w, int ln, float* s_red, float* v)
{
    #pragma unroll
    for (int j = 0; j < 8; ++j) s_red[w * BD_ + ln * 8 + j] = s_acc[j];
    __syncthreads();
    float tv[8];
    #pragma unroll
    for (int j = 0; j < 8; ++j) tv[j] = 0.f;
    #pragma unroll
    for (int ww = 0; ww < NW; ++ww) {
        #pragma unroll
        for (int j = 0; j < 8; ++j) tv[j] += s_red[ww * BD_ + ln * 8 + j];
    }
    float msq = 0.f;
    #pragma unroll
    for (int j = 0; j < 8; ++j) { tv[j] *= scale; msq += tv[j] * tv[j]; }
    __syncthreads();   // s_red reused next pass
    msq += __shfl_xor(msq, 1, 64);   // partner lane holds other half of D
    const float fac = sqrtf(msq) / (1.f + msq);   // squash: s * |s|/(1+|s|^2)
    #pragma unroll
    for (int j = 0; j < 8; ++j) v[j] = tv[j] * fac;
}

__global__ __launch_bounds__(512) void k_route(
    const uint32_t* __restrict__ po, float* __restrict__ out, int s0)
{
    const int t  = threadIdx.x;
    const int w  = t >> 6;
    const int ln = t & 63;
    const int site = s0 + blockIdx.x;

    __shared__ float s_red[NW * BD_];   // 16 KB

    const uint32_t* sbase = po + (size_t)blockIdx.x * SITE_UINTS + (size_t)ln * 4;

    float v1[8], v12[8], s_acc[8];

    // ---- pass 1: c uniform = 1/32 -> s1 -> v1
    #pragma unroll
    for (int j = 0; j < 8; ++j) s_acc[j] = 0.f;
    {
        uint4 pk = *reinterpret_cast<const uint4*>(sbase + (size_t)w * (BD_/2));
        for (int r = 0; r < NR; ++r) {
            const int rn = (r + 1 < NR) ? r + 1 : 0;
            const uint4 nxt = *reinterpret_cast<const uint4*>(
                sbase + (size_t)(rn * NW + w) * (BD_/2));
            float f[8]; decode8(pk, f);
            #pragma unroll
            for (int j = 0; j < 8; ++j) s_acc[j] += f[j];
            pk = nxt;
        }
    }
    reduce_squash(s_acc, 1.f / 32.f, w, ln, s_red, v1);

    // ---- pass 2: logits = <v1,po>, softmax over B -> s2 -> v2 (folded into v12)
    #pragma unroll
    for (int j = 0; j < 8; ++j) s_acc[j] = 0.f;
    {
        uint4 pk = *reinterpret_cast<const uint4*>(sbase + (size_t)w * (BD_/2));
        for (int r = 0; r < NR; ++r) {
            const int rn = (r + 1 < NR) ? r + 1 : 0;
            const uint4 nxt = *reinterpret_cast<const uint4*>(
                sbase + (size_t)(rn * NW + w) * (BD_/2));
            float f[8]; decode8(pk, f);
            float up = 0.f;
            #pragma unroll
            for (int j = 0; j < 8; ++j) up += v1[j] * f[j];
            up += __shfl_xor(up, 1, 64);
            float mx = up;
            #pragma unroll
            for (int m = 2; m < 64; m <<= 1) mx = fmaxf(mx, __shfl_xor(mx, m, 64));
            const float e = __expf(up - mx);
            float se = e;
            #pragma unroll
            for (int m = 2; m < 64; m <<= 1) se += __shfl_xor(se, m, 64);
            const float c = e * __builtin_amdgcn_rcpf(se);
            #pragma unroll
            for (int j = 0; j < 8; ++j) s_acc[j] += c * f[j];
            pk = nxt;
        }
    }
    reduce_squash(s_acc, 1.f, w, ln, s_red, v12);
    #pragma unroll
    for (int j = 0; j < 8; ++j) v12[j] += v1[j];   // v12 = v1 + v2

    // ---- pass 3: logits = <v1+v2,po>, softmax -> s3 -> v3
    #pragma unroll
    for (int j = 0; j < 8; ++j) s_acc[j] = 0.f;
    {
        uint4 pk = *reinterpret_cast<const uint4*>(sbase + (size_t)w * (BD_/2));
        for (int r = 0; r < NR; ++r) {
            const int rn = (r + 1 < NR) ? r + 1 : 0;
            const uint4 nxt = *reinterpret_cast<const uint4*>(
                sbase + (size_t)(rn * NW + w) * (BD_/2));
            float f[8]; decode8(pk, f);
            float up = 0.f;
            #pragma unroll
            for (int j = 0; j < 8; ++j) up += v12[j] * f[j];
            up += __shfl_xor(up, 1, 64);
            float mx = up;
            #pragma unroll
            for (int m = 2; m < 64; m <<= 1) mx = fmaxf(mx, __shfl_xor(mx, m, 64));
            const float e = __expf(up - mx);
            float se = e;
            #pragma unroll
            for (int m = 2; m < 64; m <<= 1) se += __shfl_xor(se, m, 64);
            const float c = e * __builtin_amdgcn_rcpf(se);
            #pragma unroll
            for (int j = 0; j < 8; ++j) s_acc[j] += c * f[j];
            pk = nxt;
        }
    }
    float v3[8];
    reduce_squash(s_acc, 1.f, w, ln, s_red, v3);

    // ---- write v3: out[b][bd][l], bd = ln*8+j (waves hold identical v3; w0 stores)
    if (w == 0) {
        const int b = site / L_;
        const int l = site - b * L_;
        float* op = out + (size_t)b * BD_ * L_ + l;
        #pragma unroll
        for (int j = 0; j < 8; ++j) op[(size_t)(ln * 8 + j) * L_] = v3[j];
    }
}

extern "C" void kernel_launch(void* const* d_in, const int* in_sizes, int n_in,
                              void* d_out, int out_size, void* d_ws, size_t ws_size,
                              hipStream_t stream) {
    const float* pose = (const float*)d_in[0];
    const float* W    = (const float*)d_in[1];
    float* out        = (float*)d_out;

    size_t max_chunk_sz = ws_size / (size_t)SITE_BYTES;
    int max_chunk = (max_chunk_sz > (size_t)NSITES) ? NSITES : (int)max_chunk_sz;
    if (max_chunk <= 0) return;

    for (int s0 = 0; s0 < NSITES; s0 += max_chunk) {
        const int chunk = (NSITES - s0 < max_chunk) ? (NSITES - s0) : max_chunk;
        const int s_end = s0 + chunk;
        dim3 g1((chunk + 15) / 16, KKA_ / 4, 1);
        k_pose_out<<<g1, dim3(256), 0, stream>>>(pose, W, (uint32_t*)d_ws, s0, s_end);
        k_route<<<dim3(chunk), dim3(512), 0, stream>>>((const uint32_t*)d_ws, out, s0);
    }
}